// Round 15
// baseline (91.577 us; speedup 1.0000x reference)
//
#include <hip/hip_runtime.h>

using f32x4  = __attribute__((ext_vector_type(4))) float;
using f32x16 = __attribute__((ext_vector_type(16))) float;
using bf16x8 = __attribute__((ext_vector_type(8))) short;

__device__ __forceinline__ ushort f2bf(float f) {
  union { float f; unsigned u; } v{f};
  unsigned r = v.u + 0x7FFFu + ((v.u >> 16) & 1u);   // round-nearest-even
  return (ushort)(r >> 16);
}
__device__ __forceinline__ f32x4 mfma16(bf16x8 a, bf16x8 b, f32x4 c) {
  return __builtin_amdgcn_mfma_f32_16x16x32_bf16(a, b, c, 0, 0, 0);
}
__device__ __forceinline__ f32x16 mfma32(bf16x8 a, bf16x8 b, f32x16 c) {
  return __builtin_amdgcn_mfma_f32_32x32x16_bf16(a, b, c, 0, 0, 0);
}
__device__ __forceinline__ void gload16(const ushort* g, ushort* l) {
  __builtin_amdgcn_global_load_lds(
      (const __attribute__((address_space(1))) void*)g,
      (__attribute__((address_space(3))) void*)l, 16, 0, 0);
}

// ---------------------------------------------------------------------------
// conv_qkv (prep fused, coalesced): reads fp32 x and fp32 W directly.
// A-stage: pair-wise float4 row loads (coalesced) -> packed ushort2
// transposed writes into [64 hw][32 c] stride-40 LDS (fragment addressing
// identical to the validated round-11 kernel). W converted inline.
// V epilogue stores hw-columns PERMUTED within each 16 (quads 1<->2 swapped)
// so attn's PV A-fragment is the cvt_pk words directly (zero shuffles).
// ---------------------------------------------------------------------------
__global__ __launch_bounds__(256) void conv_qkv(
    const float* __restrict__ x0, const float* __restrict__ x1,
    const float* __restrict__ x2,
    const float* __restrict__ Wqf, const float* __restrict__ Wkf,
    const float* __restrict__ Wvf,
    const float* __restrict__ bq, const float* __restrict__ bk,
    const float* __restrict__ bv,
    ushort* __restrict__ outQ, ushort* __restrict__ outK,
    ushort* __restrict__ outV)
{
  __shared__ ushort lds[18432];
  const int z = blockIdx.z, inp = z >> 3, b = z & 7;
  const int t = threadIdx.x, w = t >> 6, lane = t & 63;
  const int li = lane & 15, g = lane >> 4;
  const int o0 = blockIdx.y * 256, hw0 = blockIdx.x * 64;
  const float* xb = (inp == 0 ? x0 : inp == 1 ? x1 : x2) +
                    (size_t)b * 262144 + hw0;
  const float* wb = (inp == 0 ? Wqf : inp == 1 ? Wkf : Wvf) + (size_t)o0 * 256;
  const float* bias = (inp == 0 ? bq : inp == 1 ? bk : bv);
  ushort* out = (inp == 0 ? outQ : inp == 1 ? outK : outV);
  const float scale = (inp == 0) ? 0.125f * 1.44269504f : 1.0f;
  const int MODE = (inp == 2);
  const int srow = t >> 2, sseg = t & 3;
  const int cp = (t >> 4) * 2;           // even channel 0..30
  const int hw4 = (t & 15) * 4;          // hw offset 0..60

  f32x4 acc[4][4];
#pragma unroll
  for (int i = 0; i < 4; ++i)
#pragma unroll
    for (int j = 0; j < 4; ++j) acc[i][j] = f32x4{0.f, 0.f, 0.f, 0.f};

  for (int ks = 0; ks < 8; ++ks) {
    const int k0 = ks * 32;
    __syncthreads();
    {   // A: x fp32 rows (k0+cp, k0+cp+1) at [hw4..hw4+4) -> LDS [hw][c]
      const float4 va = *reinterpret_cast<const float4*>(
          &xb[(size_t)(k0 + cp) * 1024 + hw4]);
      const float4 vb = *reinterpret_cast<const float4*>(
          &xb[(size_t)(k0 + cp + 1) * 1024 + hw4]);
      ushort2 p;
      p.x = f2bf(va.x); p.y = f2bf(vb.x);
      *reinterpret_cast<ushort2*>(&lds[(hw4 + 0) * 40 + cp]) = p;
      p.x = f2bf(va.y); p.y = f2bf(vb.y);
      *reinterpret_cast<ushort2*>(&lds[(hw4 + 1) * 40 + cp]) = p;
      p.x = f2bf(va.z); p.y = f2bf(vb.z);
      *reinterpret_cast<ushort2*>(&lds[(hw4 + 2) * 40 + cp]) = p;
      p.x = f2bf(va.w); p.y = f2bf(vb.w);
      *reinterpret_cast<ushort2*>(&lds[(hw4 + 3) * 40 + cp]) = p;
    }
    // W: fp32 [256 o][32 c] -> bf16 rows 64..319, stride 40
#pragma unroll
    for (int it = 0; it < 4; ++it) {
      const int r = srow + it * 64;
      const float* ws = &wb[(size_t)r * 256 + k0 + sseg * 8];
      const float4 w0 = *reinterpret_cast<const float4*>(&ws[0]);
      const float4 w1 = *reinterpret_cast<const float4*>(&ws[4]);
      ushort tmp[8];
      tmp[0] = f2bf(w0.x); tmp[1] = f2bf(w0.y); tmp[2] = f2bf(w0.z); tmp[3] = f2bf(w0.w);
      tmp[4] = f2bf(w1.x); tmp[5] = f2bf(w1.y); tmp[6] = f2bf(w1.z); tmp[7] = f2bf(w1.w);
      *reinterpret_cast<uint4*>(&lds[(64 + r) * 40 + sseg * 8]) =
          *reinterpret_cast<uint4*>(&tmp[0]);
    }
    __syncthreads();
    bf16x8 af[4], bf[4];
#pragma unroll
    for (int mi = 0; mi < 4; ++mi) {
      const int ra = (!MODE) ? (mi * 16 + li) : (64 + w * 64 + mi * 16 + li);
      af[mi] = *reinterpret_cast<const bf16x8*>(&lds[ra * 40 + g * 8]);
    }
#pragma unroll
    for (int ni = 0; ni < 4; ++ni) {
      const int rb = (!MODE) ? (64 + w * 64 + ni * 16 + li) : (ni * 16 + li);
      bf[ni] = *reinterpret_cast<const bf16x8*>(&lds[rb * 40 + g * 8]);
    }
#pragma unroll
    for (int mi = 0; mi < 4; ++mi)
#pragma unroll
      for (int ni = 0; ni < 4; ++ni)
        acc[mi][ni] = mfma16(af[mi], bf[ni], acc[mi][ni]);
  }
  __syncthreads();

  if (!MODE) {
    float bb[4];
#pragma unroll
    for (int ni = 0; ni < 4; ++ni) bb[ni] = bias[o0 + w * 64 + ni * 16 + li];
#pragma unroll
    for (int mi = 0; mi < 4; ++mi)
#pragma unroll
      for (int ni = 0; ni < 4; ++ni)
#pragma unroll
        for (int r = 0; r < 4; ++r)
          lds[(mi * 16 + g * 4 + r) * 264 + w * 64 + ni * 16 + li] =
              f2bf((acc[mi][ni][r] + bb[ni]) * scale);
    __syncthreads();
    const int row = t & 63;
    ushort* dst = out + (size_t)(b * 8 + (o0 >> 6) + w) * 65536 +
                  (size_t)(hw0 + row) * 64;
#pragma unroll
    for (int seg = 0; seg < 8; ++seg)
      *reinterpret_cast<uint4*>(&dst[seg * 8]) =
          *reinterpret_cast<const uint4*>(&lds[row * 264 + w * 64 + seg * 8]);
  } else {
    // sigma: swap quads 1 and 2 within each 16 columns (PV layout match)
    const int lis = (li & 3) | ((li & 4) << 1) | ((li & 8) >> 1);
#pragma unroll
    for (int mi = 0; mi < 4; ++mi)
#pragma unroll
      for (int r = 0; r < 4; ++r) {
        const float bb = bias[o0 + w * 64 + mi * 16 + g * 4 + r];
#pragma unroll
        for (int ni = 0; ni < 4; ++ni)
          lds[w * 4608 + (mi * 16 + g * 4 + r) * 72 + ni * 16 + lis] =
              f2bf(acc[mi][ni][r] + bb);
      }
    __syncthreads();
    const int d = t & 63;
    ushort* dst = out + (size_t)(b * 8 + (o0 >> 6) + w) * 65536 +
                  (size_t)d * 1024 + hw0;
#pragma unroll
    for (int seg = 0; seg < 8; ++seg)
      *reinterpret_cast<uint4*>(&dst[seg * 8]) =
          *reinterpret_cast<const uint4*>(&lds[w * 4608 + d * 72 + seg * 8]);
  }
}

// ---------------------------------------------------------------------------
// outconv: out[b][64][1024] fp32 = Wo(64x512) . attnF(512x1024) + bo.
// 256 blocks x 128 thr; Wo read fp32 + converted inline (L2-resident).
// ---------------------------------------------------------------------------
__global__ __launch_bounds__(128) void outconv_mfma(
    const float* __restrict__ attnF, const float* __restrict__ Wof,
    const float* __restrict__ bias, float* __restrict__ out)
{
  __shared__ float ldsf[64 * 36];              // 9216 B epilogue bounce
  __shared__ ushort lds[64 * 40 + 32 * 40];    // A 2560 + B 1280 ushorts
  const int t = threadIdx.x, wv = t >> 6, lane = t & 63;
  const int li = lane & 15, g = lane >> 4;
  const int b = blockIdx.y, hw0 = blockIdx.x * 32;
  f32x4 acc[4];
#pragma unroll
  for (int i = 0; i < 4; ++i) acc[i] = f32x4{0.f, 0.f, 0.f, 0.f};

  for (int ks = 0; ks < 16; ++ks) {
    const int k0 = ks * 32;
    __syncthreads();
    {   // stage Wo [64 o][32 k] from fp32
      const int row = t & 63, sh = (t >> 6) * 16;
      const float* src = &Wof[(size_t)row * 512 + k0 + sh];
      const float4 a0 = *reinterpret_cast<const float4*>(&src[0]);
      const float4 a1 = *reinterpret_cast<const float4*>(&src[4]);
      const float4 a2 = *reinterpret_cast<const float4*>(&src[8]);
      const float4 a3 = *reinterpret_cast<const float4*>(&src[12]);
      ushort tmp[16];
      tmp[0] = f2bf(a0.x); tmp[1] = f2bf(a0.y); tmp[2] = f2bf(a0.z); tmp[3] = f2bf(a0.w);
      tmp[4] = f2bf(a1.x); tmp[5] = f2bf(a1.y); tmp[6] = f2bf(a1.z); tmp[7] = f2bf(a1.w);
      tmp[8] = f2bf(a2.x); tmp[9] = f2bf(a2.y); tmp[10] = f2bf(a2.z); tmp[11] = f2bf(a2.w);
      tmp[12] = f2bf(a3.x); tmp[13] = f2bf(a3.y); tmp[14] = f2bf(a3.z); tmp[15] = f2bf(a3.w);
      *reinterpret_cast<uint4*>(&lds[row * 40 + sh]) = *reinterpret_cast<uint4*>(&tmp[0]);
      *reinterpret_cast<uint4*>(&lds[row * 40 + sh + 8]) = *reinterpret_cast<uint4*>(&tmp[8]);
    }
    {   // stage attnF [32 k][32 hw] -> bf16 transposed [32 hw][40], octet-swz
      const int c = t >> 2, hw8 = (t & 3) * 8;
      const float* src = &attnF[((size_t)b * 512 + k0 + c) * 1024 + hw0 + hw8];
      const float4 a4 = *reinterpret_cast<const float4*>(&src[0]);
      const float4 b4 = *reinterpret_cast<const float4*>(&src[4]);
      const float vv[8] = {a4.x, a4.y, a4.z, a4.w, b4.x, b4.y, b4.z, b4.w};
#pragma unroll
      for (int e = 0; e < 8; ++e) {
        const int hw = hw8 + e;
        const int swz = c ^ (((hw >> 2) & 3) << 3);
        lds[2560 + hw * 40 + swz] = f2bf(vv[e]);
      }
    }
    __syncthreads();
    const bf16x8 bfg = *reinterpret_cast<const bf16x8*>(
        &lds[2560 + (wv * 16 + li) * 40 + 8 * (g ^ ((li >> 2) & 3))]);
#pragma unroll
    for (int mi = 0; mi < 4; ++mi) {
      const bf16x8 af = *reinterpret_cast<const bf16x8*>(&lds[(mi * 16 + li) * 40 + g * 8]);
      acc[mi] = mfma16(af, bfg, acc[mi]);
    }
  }
  __syncthreads();
#pragma unroll
  for (int mi = 0; mi < 4; ++mi)
#pragma unroll
    for (int r = 0; r < 4; ++r)
      ldsf[(mi * 16 + g * 4 + r) * 36 + wv * 16 + li] =
          acc[mi][r] + bias[mi * 16 + g * 4 + r];
  __syncthreads();
  const int o = t >> 1, half = (t & 1) * 16;
  float* dst = out + ((size_t)b * 64 + o) * 1024 + hw0 + half;
#pragma unroll
  for (int f = 0; f < 4; ++f)
    *reinterpret_cast<float4*>(&dst[f * 4]) =
        *reinterpret_cast<const float4*>(&ldsf[o * 36 + half + f * 4]);
}

// ---------------------------------------------------------------------------
// 32x32 flash attention (round-11 verified version, unchanged): no max
// tracking, zero-shuffle PV, bare v_exp_f32, 4-way psum tree.
// Arena 50176 B: kv0 | kv1 | rhc[128][34]; rw scratch aliases kv1+rhc.
// Grid 512 flat: bn = bid&63 -> 8 q-tile blocks of one bn on one XCD.
// ---------------------------------------------------------------------------
__global__ __launch_bounds__(256, 3) void attn_mfma(
    const ushort* __restrict__ qg, const ushort* __restrict__ kg,
    const ushort* __restrict__ vg, const float* __restrict__ relw,
    const float* __restrict__ relh, float* __restrict__ attn)
{
  __shared__ __align__(16) unsigned char smem[50176];
  ushort* kv0 = (ushort*)smem;                     // [0, 16384)
  ushort* kv1 = (ushort*)(smem + 16384);           // [16384, 32768)
  float*  scratch = (float*)(smem + 16384);        // build-only, 128x66 = 33792 B
  float*  rhc = (float*)(smem + 32768);            // [128][34], persistent

  const int bid = blockIdx.x;
  const int bn = bid & 63;
  const int qb = (bid >> 6) * 128;
  const int tid = threadIdx.x;
  const int w = tid >> 6, lane = tid & 63;
  const int li32 = lane & 31, h = lane >> 5;
  const int so = lane & 7;

  const ushort* qbn = qg + (size_t)bn * 65536;
  const ushort* kbn = kg + (size_t)bn * 65536;
  const ushort* vbn = vg + (size_t)bn * 65536;

  const int ldr = lane >> 3;
  auto stage = [&](int cc) {
    ushort* dst = (cc & 1) ? kv1 : kv0;
    if (w < 2) {
#pragma unroll
      for (int inst = 0; inst < 4; ++inst) {
        const int row = w * 32 + inst * 8 + ldr;
        const int col8 = ((lane & 7) ^ (row & 7)) * 8;
        gload16(&kbn[(cc * 64 + row) * 64 + col8],
                &dst[(w * 32 + inst * 8) * 64]);
      }
    } else {
#pragma unroll
      for (int inst = 0; inst < 4; ++inst) {
        const int dv = (w - 2) * 32 + inst * 8 + ldr;
        const int col8 = ((lane & 7) ^ (dv & 7)) * 8;
        gload16(&vbn[dv * 1024 + cc * 64 + col8],
                &dst[4096 + ((w - 2) * 32 + inst * 8) * 64]);
      }
    }
  };

  stage(0);   // writes kv0; flies under the table build

  const int qi = qb + w * 32 + li32;
  bf16x8 qf[4];
#pragma unroll
  for (int ks = 0; ks < 4; ++ks)
    qf[ks] = *reinterpret_cast<const bf16x8*>(&qbn[qi * 64 + ks * 16 + 8 * h]);

  const int xq = (qb + w * 32) >> 5;           // wave-uniform query x-coord

  // ---- Phase RW: build into scratch (store stride 66), extract 16 regs ----
  float* tbw = scratch + (size_t)(w * 32) * 66;
  float rwv[16];
#pragma unroll
  for (int mt = 0; mt < 2; ++mt) {
    f32x16 d;
#pragma unroll
    for (int e = 0; e < 16; ++e) d[e] = 0.f;
    const int mm = min(mt * 32 + li32, 62);
#pragma unroll
    for (int ks = 0; ks < 4; ++ks) {
      float tmp[8];
      *reinterpret_cast<float4*>(&tmp[0]) =
          *reinterpret_cast<const float4*>(&relw[mm * 64 + ks * 16 + 8 * h]);
      *reinterpret_cast<float4*>(&tmp[4]) =
          *reinterpret_cast<const float4*>(&relw[mm * 64 + ks * 16 + 8 * h + 4]);
      bf16x8 af;
#pragma unroll
      for (int e = 0; e < 8; ++e) af[e] = (short)f2bf(tmp[e]);
      d = mfma32(af, qf[ks], d);
    }
#pragma unroll
    for (int r = 0; r < 16; ++r)
      tbw[li32 * 66 + mt * 32 + ((r & 3) + 8 * (r >> 2) + 4 * h)] = d[r];
  }
  asm volatile("s_waitcnt lgkmcnt(0)" ::: "memory");
  __builtin_amdgcn_sched_barrier(0);
  // diagonal read of the stride-66 table: addr = i*65 + x -> [i][x - i];
  // 65 = 1 mod 32 -> 32 lanes hit 32 distinct banks (conflict-free)
#pragma unroll
  for (int r = 0; r < 16; ++r)
    rwv[r] = tbw[li32 * 65 + ((r & 3) + 8 * (r >> 2) + 4 * h) + 31];
  asm volatile("s_waitcnt lgkmcnt(0)" ::: "memory");
  __builtin_amdgcn_sched_barrier(0);
  __syncthreads();   // all rw extractions done before rh overlays scratch tail

  // ---- Phase RH: build directly into compact window (idx = m-31+xq) ----
#pragma unroll
  for (int mt = 0; mt < 2; ++mt) {
    f32x16 d;
#pragma unroll
    for (int e = 0; e < 16; ++e) d[e] = 0.f;
    const int mm = min(mt * 32 + li32, 62);
#pragma unroll
    for (int ks = 0; ks < 4; ++ks) {
      float tmp[8];
      *reinterpret_cast<float4*>(&tmp[0]) =
          *reinterpret_cast<const float4*>(&relh[mm * 64 + ks * 16 + 8 * h]);
      *reinterpret_cast<float4*>(&tmp[4]) =
          *reinterpret_cast<const float4*>(&relh[mm * 64 + ks * 16 + 8 * h + 4]);
      bf16x8 af;
#pragma unroll
      for (int e = 0; e < 8; ++e) af[e] = (short)f2bf(tmp[e]);
      d = mfma32(af, qf[ks], d);
    }
#pragma unroll
    for (int r = 0; r < 16; ++r) {
      const int m = mt * 32 + ((r & 3) + 8 * (r >> 2) + 4 * h);
      const int idx = m - 31 + xq;
      if ((unsigned)idx < 32u)
        rhc[(w * 32 + li32) * 34 + idx] = d[r];
    }
  }
  asm volatile("s_waitcnt lgkmcnt(0)" ::: "memory");
  __builtin_amdgcn_sched_barrier(0);

  f32x16 oacc0, oacc1;
#pragma unroll
  for (int e = 0; e < 16; ++e) { oacc0[e] = 0.f; oacc1[e] = 0.f; }
  float lrun = 0.f;                            // per-lane (half-row) sum

  for (int c = 0; c < 16; ++c) {
    __syncthreads();
    if (c < 15) stage(c + 1);
    const ushort* Kb = (c & 1) ? kv1 : kv0;
    const ushort* Vb = Kb + 4096;

    // ---- QK^T with rel logits as the C-initializer ----
    const float2 rhv = *reinterpret_cast<const float2*>(
        &rhc[(w * 32 + li32) * 34 + 2 * c]);
    f32x16 s0, s1;
#pragma unroll
    for (int r = 0; r < 16; ++r) { s0[r] = rwv[r] + rhv.x; s1[r] = rwv[r] + rhv.y; }
    __builtin_amdgcn_s_setprio(1);
#pragma unroll
    for (int ks = 0; ks < 4; ++ks) {
      const int oct = ((2 * ks + h) ^ so) * 8;
      const bf16x8 k0 = *reinterpret_cast<const bf16x8*>(&Kb[li32 * 64 + oct]);
      const bf16x8 k1 = *reinterpret_cast<const bf16x8*>(&Kb[(32 + li32) * 64 + oct]);
      s0 = mfma32(k0, qf[ks], s0);
      s1 = mfma32(k1, qf[ks], s1);
    }
    __builtin_amdgcn_s_setprio(0);

    // ---- exp2 (bare v_exp_f32, no max) + 4-way psum tree ----
#pragma unroll
    for (int r = 0; r < 16; ++r) {
      s0[r] = __builtin_amdgcn_exp2f(s0[r]);
      s1[r] = __builtin_amdgcn_exp2f(s1[r]);
    }
    {
      float q0 = 0.f, q1 = 0.f, q2 = 0.f, q3 = 0.f;
#pragma unroll
      for (int r = 0; r < 16; r += 4) {
        q0 += s0[r + 0] + s1[r + 0];
        q1 += s0[r + 1] + s1[r + 1];
        q2 += s0[r + 2] + s1[r + 2];
        q3 += s0[r + 3] + s1[r + 3];
      }
      lrun += (q0 + q1) + (q2 + q3);
    }

    // ---- P -> bf16 packs; pa = words directly (V quad-permuted) ----
    uint pk0[4][2], pk1[4][2];
#pragma unroll
    for (int J = 0; J < 4; ++J) {
      asm("v_cvt_pk_bf16_f32 %0, %1, %2" : "=v"(pk0[J][0]) : "v"(s0[4 * J]), "v"(s0[4 * J + 1]));
      asm("v_cvt_pk_bf16_f32 %0, %1, %2" : "=v"(pk0[J][1]) : "v"(s0[4 * J + 2]), "v"(s0[4 * J + 3]));
      asm("v_cvt_pk_bf16_f32 %0, %1, %2" : "=v"(pk1[J][0]) : "v"(s1[4 * J]), "v"(s1[4 * J + 1]));
      asm("v_cvt_pk_bf16_f32 %0, %1, %2" : "=v"(pk1[J][1]) : "v"(s1[4 * J + 2]), "v"(s1[4 * J + 3]));
    }

    __builtin_amdgcn_s_setprio(1);
#pragma unroll
    for (int ks = 0; ks < 4; ++ks) {
      const int kk = ks & 1;
      uint fu[4];
      if (ks < 2) {
        fu[0] = pk0[2 * kk][0]; fu[1] = pk0[2 * kk][1];
        fu[2] = pk0[2 * kk + 1][0]; fu[3] = pk0[2 * kk + 1][1];
      } else {
        fu[0] = pk1[2 * kk][0]; fu[1] = pk1[2 * kk][1];
        fu[2] = pk1[2 * kk + 1][0]; fu[3] = pk1[2 * kk + 1][1];
      }
      const bf16x8 pa = *reinterpret_cast<const bf16x8*>(&fu[0]);
      const int oct = ((2 * ks + h) ^ so) * 8;
      const bf16x8 v0 = *reinterpret_cast<const bf16x8*>(&Vb[li32 * 64 + oct]);
      const bf16x8 v1 = *reinterpret_cast<const bf16x8*>(&Vb[(32 + li32) * 64 + oct]);
      oacc0 = mfma32(pa, v0, oacc0);
      oacc1 = mfma32(pa, v1, oacc1);
    }
    __builtin_amdgcn_s_setprio(0);
  }

  // ---- finalize: combine half-row sums once, divide, store ----
  const float lt = lrun + __shfl_xor(lrun, 32);
  float* ob = attn + (size_t)bn * 65536;
#pragma unroll
  for (int r = 0; r < 16; ++r) {
    const int rp = (r & 3) + 8 * (r >> 2) + 4 * h;
    const float linv = 1.0f / __shfl(lt, rp);
    const size_t qrow = (size_t)(qb + w * 32 + rp) * 64;
    ob[qrow + li32] = oacc0[r] * linv;
    ob[qrow + 32 + li32] = oacc1[r] * linv;
  }
}

// ---------------------------------------------------------------------------
extern "C" void kernel_launch(void* const* d_in, const int* in_sizes, int n_in,
                              void* d_out, int out_size, void* d_ws, size_t ws_size,
                              hipStream_t stream) {
  const float* q_x = (const float*)d_in[0];
  const float* k_x = (const float*)d_in[1];
  const float* v_x = (const float*)d_in[2];
  const float* Wq  = (const float*)d_in[3];
  const float* bq  = (const float*)d_in[4];
  const float* Wk  = (const float*)d_in[5];
  const float* bk  = (const float*)d_in[6];
  const float* Wv  = (const float*)d_in[7];
  const float* bv  = (const float*)d_in[8];
  const float* Wo  = (const float*)d_in[9];
  const float* bo  = (const float*)d_in[10];
  const float* krw = (const float*)d_in[11];
  const float* krh = (const float*)d_in[12];

  ushort* wsQ  = (ushort*)d_ws;                 // [64][1024][64] bf16   8 MB
  ushort* wsK  = wsQ + 4194304;                 // 8 MB
  ushort* wsV  = wsK + 4194304;                 // [64][64][1024] bf16   8 MB
  float*  attnF = (float*)(wsV + 4194304);      // [8][512][1024] fp32  16 MB

  conv_qkv<<<dim3(16, 2, 24), 256, 0, stream>>>(q_x, k_x, v_x, Wq, Wk, Wv,
                                                bq, bk, bv, wsQ, wsK, wsV);

  attn_mfma<<<512, 256, 0, stream>>>(wsQ, wsK, wsV, krw, krh, attnF);

  outconv_mfma<<<dim3(32, 8), 128, 0, stream>>>(attnF, Wo, bo, (float*)d_out);
}

// Round 16
// 79.692 us; speedup vs baseline: 1.1491x; 1.1491x over previous
//
#include <hip/hip_runtime.h>

using f32x4  = __attribute__((ext_vector_type(4))) float;
using f32x16 = __attribute__((ext_vector_type(16))) float;
using bf16x8 = __attribute__((ext_vector_type(8))) short;

__device__ __forceinline__ ushort f2bf(float f) {
  union { float f; unsigned u; } v{f};
  unsigned r = v.u + 0x7FFFu + ((v.u >> 16) & 1u);   // round-nearest-even
  return (ushort)(r >> 16);
}
__device__ __forceinline__ ushort4 f4bf(float4 f) {
  ushort4 r; r.x = f2bf(f.x); r.y = f2bf(f.y); r.z = f2bf(f.z); r.w = f2bf(f.w); return r;
}
__device__ __forceinline__ f32x4 mfma16(bf16x8 a, bf16x8 b, f32x4 c) {
  return __builtin_amdgcn_mfma_f32_16x16x32_bf16(a, b, c, 0, 0, 0);
}
__device__ __forceinline__ f32x16 mfma32(bf16x8 a, bf16x8 b, f32x16 c) {
  return __builtin_amdgcn_mfma_f32_32x32x16_bf16(a, b, c, 0, 0, 0);
}
__device__ __forceinline__ void gload16(const ushort* g, ushort* l) {
  __builtin_amdgcn_global_load_lds(
      (const __attribute__((address_space(1))) void*)g,
      (__attribute__((address_space(3))) void*)l, 16, 0, 0);
}

// ---------------------------------------------------------------------------
// prep_all: [0,1536) = transpose x->xT bf16; [1536,1744) = weights fp32->bf16
// ---------------------------------------------------------------------------
__global__ __launch_bounds__(256) void prep_all(
    const float* __restrict__ x0, const float* __restrict__ x1,
    const float* __restrict__ x2,
    const float* __restrict__ Wq, const float* __restrict__ Wk,
    const float* __restrict__ Wv, const float* __restrict__ Wo,
    ushort* __restrict__ xT, ushort* __restrict__ Wdst)
{
  __shared__ ushort sT[64 * 72];
  const int bi = blockIdx.x;
  const int t = threadIdx.x;
  if (bi < 1536) {
    const int hw0 = (bi & 15) * 64;
    const int rest = bi >> 4;            // 0..95
    const int y = rest % 12, b = rest / 12;
    const int inp = y >> 2, c0 = (y & 3) * 64;
    const float* src = (inp == 0 ? x0 : inp == 1 ? x1 : x2) +
                       ((size_t)b * 256 + c0) * 1024 + hw0;
    const int clb = t >> 4, hwl = (t & 15) * 4;
#pragma unroll
    for (int cc = 0; cc < 4; ++cc) {
      const int cl = clb + cc * 16;
      const float4 v = *reinterpret_cast<const float4*>(&src[(size_t)cl * 1024 + hwl]);
      *reinterpret_cast<ushort4*>(&sT[cl * 72 + hwl]) = f4bf(v);
    }
    __syncthreads();
    const int hv = t >> 2, cs = (t & 3) * 16;
    ushort tmp[16];
#pragma unroll
    for (int j = 0; j < 16; ++j) tmp[j] = sT[(cs + j) * 72 + hv];
    ushort* dst = xT + (size_t)inp * 2097152 +
                  ((size_t)b * 1024 + hw0 + hv) * 256 + c0 + cs;
    *reinterpret_cast<uint4*>(&dst[0]) = *reinterpret_cast<uint4*>(&tmp[0]);
    *reinterpret_cast<uint4*>(&dst[8]) = *reinterpret_cast<uint4*>(&tmp[8]);
  } else {
    const int idx = ((bi - 1536) * 256 + t) * 8;
    const int r = idx >> 17;
    const float* src = (r == 0 ? Wq : r == 1 ? Wk : r == 2 ? Wv : Wo) + (idx - r * 131072);
    const float4 a = *reinterpret_cast<const float4*>(&src[0]);
    const float4 b = *reinterpret_cast<const float4*>(&src[4]);
    ushort tmp[8];
    *reinterpret_cast<ushort4*>(&tmp[0]) = f4bf(a);
    *reinterpret_cast<ushort4*>(&tmp[4]) = f4bf(b);
    *reinterpret_cast<uint4*>(&Wdst[idx]) = *reinterpret_cast<uint4*>(&tmp[0]);
  }
}

// ---------------------------------------------------------------------------
// conv_qkv: all three projections in one launch. z: inp = z>>3, b = z&7.
// V epilogue stores hw-columns PERMUTED within each 16 (quads 1<->2 swapped)
// so attn's PV A-fragment is the cvt_pk words directly (zero shuffles).
// ---------------------------------------------------------------------------
__global__ __launch_bounds__(256) void conv_qkv(
    const ushort* __restrict__ xT, const ushort* __restrict__ WsBf,
    const float* __restrict__ bq, const float* __restrict__ bk,
    const float* __restrict__ bv,
    ushort* __restrict__ outQ, ushort* __restrict__ outK,
    ushort* __restrict__ outV)
{
  __shared__ ushort lds[18432];
  const int z = blockIdx.z, inp = z >> 3, b = z & 7;
  const int t = threadIdx.x, w = t >> 6, lane = t & 63;
  const int li = lane & 15, g = lane >> 4;
  const int o0 = blockIdx.y * 256, hw0 = blockIdx.x * 64;
  const ushort* xb = xT + (size_t)inp * 2097152 + ((size_t)b * 1024 + hw0) * 256;
  const ushort* wb = WsBf + (size_t)inp * 131072 + (size_t)o0 * 256;
  const float* bias = (inp == 0 ? bq : inp == 1 ? bk : bv);
  ushort* out = (inp == 0 ? outQ : inp == 1 ? outK : outV);
  const float scale = (inp == 0) ? 0.125f * 1.44269504f : 1.0f;
  const int MODE = (inp == 2);
  const int srow = t >> 2, sseg = t & 3;

  f32x4 acc[4][4];
#pragma unroll
  for (int i = 0; i < 4; ++i)
#pragma unroll
    for (int j = 0; j < 4; ++j) acc[i][j] = f32x4{0.f, 0.f, 0.f, 0.f};

  for (int ks = 0; ks < 8; ++ks) {
    const int k0 = ks * 32;
    __syncthreads();
    *reinterpret_cast<uint4*>(&lds[srow * 40 + sseg * 8]) =
        *reinterpret_cast<const uint4*>(&xb[(size_t)srow * 256 + k0 + sseg * 8]);
#pragma unroll
    for (int it = 0; it < 4; ++it) {
      const int r = srow + it * 64;
      *reinterpret_cast<uint4*>(&lds[(64 + r) * 40 + sseg * 8]) =
          *reinterpret_cast<const uint4*>(&wb[(size_t)r * 256 + k0 + sseg * 8]);
    }
    __syncthreads();
    bf16x8 af[4], bf[4];
#pragma unroll
    for (int mi = 0; mi < 4; ++mi) {
      const int ra = (!MODE) ? (mi * 16 + li) : (64 + w * 64 + mi * 16 + li);
      af[mi] = *reinterpret_cast<const bf16x8*>(&lds[ra * 40 + g * 8]);
    }
#pragma unroll
    for (int ni = 0; ni < 4; ++ni) {
      const int rb = (!MODE) ? (64 + w * 64 + ni * 16 + li) : (ni * 16 + li);
      bf[ni] = *reinterpret_cast<const bf16x8*>(&lds[rb * 40 + g * 8]);
    }
#pragma unroll
    for (int mi = 0; mi < 4; ++mi)
#pragma unroll
      for (int ni = 0; ni < 4; ++ni)
        acc[mi][ni] = mfma16(af[mi], bf[ni], acc[mi][ni]);
  }
  __syncthreads();

  if (!MODE) {
    float bb[4];
#pragma unroll
    for (int ni = 0; ni < 4; ++ni) bb[ni] = bias[o0 + w * 64 + ni * 16 + li];
#pragma unroll
    for (int mi = 0; mi < 4; ++mi)
#pragma unroll
      for (int ni = 0; ni < 4; ++ni)
#pragma unroll
        for (int r = 0; r < 4; ++r)
          lds[(mi * 16 + g * 4 + r) * 264 + w * 64 + ni * 16 + li] =
              f2bf((acc[mi][ni][r] + bb[ni]) * scale);
    __syncthreads();
    const int row = t & 63;
    ushort* dst = out + (size_t)(b * 8 + (o0 >> 6) + w) * 65536 +
                  (size_t)(hw0 + row) * 64;
#pragma unroll
    for (int seg = 0; seg < 8; ++seg)
      *reinterpret_cast<uint4*>(&dst[seg * 8]) =
          *reinterpret_cast<const uint4*>(&lds[row * 264 + w * 64 + seg * 8]);
  } else {
    // sigma: swap quads 1 and 2 within each 16 columns (PV layout match)
    const int lis = (li & 3) | ((li & 4) << 1) | ((li & 8) >> 1);
#pragma unroll
    for (int mi = 0; mi < 4; ++mi)
#pragma unroll
      for (int r = 0; r < 4; ++r) {
        const float bb = bias[o0 + w * 64 + mi * 16 + g * 4 + r];
#pragma unroll
        for (int ni = 0; ni < 4; ++ni)
          lds[w * 4608 + (mi * 16 + g * 4 + r) * 72 + ni * 16 + lis] =
              f2bf(acc[mi][ni][r] + bb);
      }
    __syncthreads();
    const int d = t & 63;
    ushort* dst = out + (size_t)(b * 8 + (o0 >> 6) + w) * 65536 +
                  (size_t)d * 1024 + hw0;
#pragma unroll
    for (int seg = 0; seg < 8; ++seg)
      *reinterpret_cast<uint4*>(&dst[seg * 8]) =
          *reinterpret_cast<const uint4*>(&lds[w * 4608 + d * 72 + seg * 8]);
  }
}

// ---------------------------------------------------------------------------
// outconv: out[b][64][1024] fp32 = Wo(64x512) . attnB(512x1024 bf16) + bo.
// 256 blocks x 128 thr; attnB read as uint4 (no convert in staging).
// ---------------------------------------------------------------------------
__global__ __launch_bounds__(128) void outconv_mfma(
    const ushort* __restrict__ attnB,  // [8][512][1024] bf16
    const ushort* __restrict__ Wob,
    const float* __restrict__ bias, float* __restrict__ out)
{
  __shared__ float ldsf[64 * 36];              // 9216 B epilogue bounce
  __shared__ ushort lds[64 * 40 + 32 * 40];    // A 2560 + B 1280 ushorts
  const int t = threadIdx.x, wv = t >> 6, lane = t & 63;
  const int li = lane & 15, g = lane >> 4;
  const int b = blockIdx.y, hw0 = blockIdx.x * 32;
  f32x4 acc[4];
#pragma unroll
  for (int i = 0; i < 4; ++i) acc[i] = f32x4{0.f, 0.f, 0.f, 0.f};

  for (int ks = 0; ks < 16; ++ks) {
    const int k0 = ks * 32;
    __syncthreads();
    {   // stage Wo [64 o][32 k]
      const int row = t & 63, sh = (t >> 6) * 16;
      *reinterpret_cast<uint4*>(&lds[row * 40 + sh]) =
          *reinterpret_cast<const uint4*>(&Wob[(size_t)row * 512 + k0 + sh]);
      *reinterpret_cast<uint4*>(&lds[row * 40 + sh + 8]) =
          *reinterpret_cast<const uint4*>(&Wob[(size_t)row * 512 + k0 + sh + 8]);
    }
    {   // stage attnB [32 k][32 hw] bf16 -> transposed [32 hw][40], octet-swz
      const int c = t >> 2, hw8 = (t & 3) * 8;
      uint4 raw = *reinterpret_cast<const uint4*>(
          &attnB[((size_t)b * 512 + k0 + c) * 1024 + hw0 + hw8]);
      const ushort* vv = reinterpret_cast<const ushort*>(&raw);
#pragma unroll
      for (int e = 0; e < 8; ++e) {
        const int hw = hw8 + e;
        const int swz = c ^ (((hw >> 2) & 3) << 3);
        lds[2560 + hw * 40 + swz] = vv[e];
      }
    }
    __syncthreads();
    const bf16x8 bfg = *reinterpret_cast<const bf16x8*>(
        &lds[2560 + (wv * 16 + li) * 40 + 8 * (g ^ ((li >> 2) & 3))]);
#pragma unroll
    for (int mi = 0; mi < 4; ++mi) {
      const bf16x8 af = *reinterpret_cast<const bf16x8*>(&lds[(mi * 16 + li) * 40 + g * 8]);
      acc[mi] = mfma16(af, bfg, acc[mi]);
    }
  }
  __syncthreads();
#pragma unroll
  for (int mi = 0; mi < 4; ++mi)
#pragma unroll
    for (int r = 0; r < 4; ++r)
      ldsf[(mi * 16 + g * 4 + r) * 36 + wv * 16 + li] =
          acc[mi][r] + bias[mi * 16 + g * 4 + r];
  __syncthreads();
  const int o = t >> 1, half = (t & 1) * 16;
  float* dst = out + ((size_t)b * 64 + o) * 1024 + hw0 + half;
#pragma unroll
  for (int f = 0; f < 4; ++f)
    *reinterpret_cast<float4*>(&dst[f * 4]) =
        *reinterpret_cast<const float4*>(&ldsf[o * 36 + half + f * 4]);
}

// ---------------------------------------------------------------------------
// 32x32 flash attention (round-11 verified structure): no max tracking,
// zero-shuffle PV, bare v_exp_f32, 4-way psum tree. NEW: output stored bf16
// (halves intermediate write+read traffic; outconv consumes bf16 directly).
// Arena 50176 B: kv0 | kv1 | rhc[128][34]; rw scratch aliases kv1+rhc.
// Grid 512 flat: bn = bid&63 -> 8 q-tile blocks of one bn on one XCD.
// ---------------------------------------------------------------------------
__global__ __launch_bounds__(256, 3) void attn_mfma(
    const ushort* __restrict__ qg, const ushort* __restrict__ kg,
    const ushort* __restrict__ vg, const float* __restrict__ relw,
    const float* __restrict__ relh, ushort* __restrict__ attnB)
{
  __shared__ __align__(16) unsigned char smem[50176];
  ushort* kv0 = (ushort*)smem;                     // [0, 16384)
  ushort* kv1 = (ushort*)(smem + 16384);           // [16384, 32768)
  float*  scratch = (float*)(smem + 16384);        // build-only, 128x66 = 33792 B
  float*  rhc = (float*)(smem + 32768);            // [128][34], persistent

  const int bid = blockIdx.x;
  const int bn = bid & 63;
  const int qb = (bid >> 6) * 128;
  const int tid = threadIdx.x;
  const int w = tid >> 6, lane = tid & 63;
  const int li32 = lane & 31, h = lane >> 5;
  const int so = lane & 7;

  const ushort* qbn = qg + (size_t)bn * 65536;
  const ushort* kbn = kg + (size_t)bn * 65536;
  const ushort* vbn = vg + (size_t)bn * 65536;

  const int ldr = lane >> 3;
  auto stage = [&](int cc) {
    ushort* dst = (cc & 1) ? kv1 : kv0;
    if (w < 2) {
#pragma unroll
      for (int inst = 0; inst < 4; ++inst) {
        const int row = w * 32 + inst * 8 + ldr;
        const int col8 = ((lane & 7) ^ (row & 7)) * 8;
        gload16(&kbn[(cc * 64 + row) * 64 + col8],
                &dst[(w * 32 + inst * 8) * 64]);
      }
    } else {
#pragma unroll
      for (int inst = 0; inst < 4; ++inst) {
        const int dv = (w - 2) * 32 + inst * 8 + ldr;
        const int col8 = ((lane & 7) ^ (dv & 7)) * 8;
        gload16(&vbn[dv * 1024 + cc * 64 + col8],
                &dst[4096 + ((w - 2) * 32 + inst * 8) * 64]);
      }
    }
  };

  stage(0);   // writes kv0; flies under the table build

  const int qi = qb + w * 32 + li32;
  bf16x8 qf[4];
#pragma unroll
  for (int ks = 0; ks < 4; ++ks)
    qf[ks] = *reinterpret_cast<const bf16x8*>(&qbn[qi * 64 + ks * 16 + 8 * h]);

  const int xq = (qb + w * 32) >> 5;           // wave-uniform query x-coord

  // ---- Phase RW: build into scratch (store stride 66), extract 16 regs ----
  float* tbw = scratch + (size_t)(w * 32) * 66;
  float rwv[16];
#pragma unroll
  for (int mt = 0; mt < 2; ++mt) {
    f32x16 d;
#pragma unroll
    for (int e = 0; e < 16; ++e) d[e] = 0.f;
    const int mm = min(mt * 32 + li32, 62);
#pragma unroll
    for (int ks = 0; ks < 4; ++ks) {
      float tmp[8];
      *reinterpret_cast<float4*>(&tmp[0]) =
          *reinterpret_cast<const float4*>(&relw[mm * 64 + ks * 16 + 8 * h]);
      *reinterpret_cast<float4*>(&tmp[4]) =
          *reinterpret_cast<const float4*>(&relw[mm * 64 + ks * 16 + 8 * h + 4]);
      bf16x8 af;
#pragma unroll
      for (int e = 0; e < 8; ++e) af[e] = (short)f2bf(tmp[e]);
      d = mfma32(af, qf[ks], d);
    }
#pragma unroll
    for (int r = 0; r < 16; ++r)
      tbw[li32 * 66 + mt * 32 + ((r & 3) + 8 * (r >> 2) + 4 * h)] = d[r];
  }
  asm volatile("s_waitcnt lgkmcnt(0)" ::: "memory");
  __builtin_amdgcn_sched_barrier(0);
  // diagonal read of the stride-66 table: addr = i*65 + x -> [i][x - i];
  // 65 = 1 mod 32 -> 32 lanes hit 32 distinct banks (conflict-free)
#pragma unroll
  for (int r = 0; r < 16; ++r)
    rwv[r] = tbw[li32 * 65 + ((r & 3) + 8 * (r >> 2) + 4 * h) + 31];
  asm volatile("s_waitcnt lgkmcnt(0)" ::: "memory");
  __builtin_amdgcn_sched_barrier(0);
  __syncthreads();   // all rw extractions done before rh overlays scratch tail

  // ---- Phase RH: build directly into compact window (idx = m-31+xq) ----
#pragma unroll
  for (int mt = 0; mt < 2; ++mt) {
    f32x16 d;
#pragma unroll
    for (int e = 0; e < 16; ++e) d[e] = 0.f;
    const int mm = min(mt * 32 + li32, 62);
#pragma unroll
    for (int ks = 0; ks < 4; ++ks) {
      float tmp[8];
      *reinterpret_cast<float4*>(&tmp[0]) =
          *reinterpret_cast<const float4*>(&relh[mm * 64 + ks * 16 + 8 * h]);
      *reinterpret_cast<float4*>(&tmp[4]) =
          *reinterpret_cast<const float4*>(&relh[mm * 64 + ks * 16 + 8 * h + 4]);
      bf16x8 af;
#pragma unroll
      for (int e = 0; e < 8; ++e) af[e] = (short)f2bf(tmp[e]);
      d = mfma32(af, qf[ks], d);
    }
#pragma unroll
    for (int r = 0; r < 16; ++r) {
      const int m = mt * 32 + ((r & 3) + 8 * (r >> 2) + 4 * h);
      const int idx = m - 31 + xq;
      if ((unsigned)idx < 32u)
        rhc[(w * 32 + li32) * 34 + idx] = d[r];
    }
  }
  asm volatile("s_waitcnt lgkmcnt(0)" ::: "memory");
  __builtin_amdgcn_sched_barrier(0);

  f32x16 oacc0, oacc1;
#pragma unroll
  for (int e = 0; e < 16; ++e) { oacc0[e] = 0.f; oacc1[e] = 0.f; }
  float lrun = 0.f;                            // per-lane (half-row) sum

  for (int c = 0; c < 16; ++c) {
    __syncthreads();
    if (c < 15) stage(c + 1);
    const ushort* Kb = (c & 1) ? kv1 : kv0;
    const ushort* Vb = Kb + 4096;

    // ---- QK^T with rel logits as the C-initializer ----
    const float2 rhv = *reinterpret_cast<const float2*>(
        &rhc[(w * 32 + li32) * 34 + 2 * c]);
    f32x16 s0, s1;
#pragma unroll
    for (int r = 0; r < 16; ++r) { s0[r] = rwv[r] + rhv.x; s1[r] = rwv[r] + rhv.y; }
    __builtin_amdgcn_s_setprio(1);
#pragma unroll
    for (int ks = 0; ks < 4; ++ks) {
      const int oct = ((2 * ks + h) ^ so) * 8;
      const bf16x8 k0 = *reinterpret_cast<const bf16x8*>(&Kb[li32 * 64 + oct]);
      const bf16x8 k1 = *reinterpret_cast<const bf16x8*>(&Kb[(32 + li32) * 64 + oct]);
      s0 = mfma32(k0, qf[ks], s0);
      s1 = mfma32(k1, qf[ks], s1);
    }
    __builtin_amdgcn_s_setprio(0);

    // ---- exp2 (bare v_exp_f32, no max) + 4-way psum tree ----
#pragma unroll
    for (int r = 0; r < 16; ++r) {
      s0[r] = __builtin_amdgcn_exp2f(s0[r]);
      s1[r] = __builtin_amdgcn_exp2f(s1[r]);
    }
    {
      float q0 = 0.f, q1 = 0.f, q2 = 0.f, q3 = 0.f;
#pragma unroll
      for (int r = 0; r < 16; r += 4) {
        q0 += s0[r + 0] + s1[r + 0];
        q1 += s0[r + 1] + s1[r + 1];
        q2 += s0[r + 2] + s1[r + 2];
        q3 += s0[r + 3] + s1[r + 3];
      }
      lrun += (q0 + q1) + (q2 + q3);
    }

    // ---- P -> bf16 packs; pa = words directly (V quad-permuted) ----
    uint pk0[4][2], pk1[4][2];
#pragma unroll
    for (int J = 0; J < 4; ++J) {
      asm("v_cvt_pk_bf16_f32 %0, %1, %2" : "=v"(pk0[J][0]) : "v"(s0[4 * J]), "v"(s0[4 * J + 1]));
      asm("v_cvt_pk_bf16_f32 %0, %1, %2" : "=v"(pk0[J][1]) : "v"(s0[4 * J + 2]), "v"(s0[4 * J + 3]));
      asm("v_cvt_pk_bf16_f32 %0, %1, %2" : "=v"(pk1[J][0]) : "v"(s1[4 * J]), "v"(s1[4 * J + 1]));
      asm("v_cvt_pk_bf16_f32 %0, %1, %2" : "=v"(pk1[J][1]) : "v"(s1[4 * J + 2]), "v"(s1[4 * J + 3]));
    }

    __builtin_amdgcn_s_setprio(1);
#pragma unroll
    for (int ks = 0; ks < 4; ++ks) {
      const int kk = ks & 1;
      uint fu[4];
      if (ks < 2) {
        fu[0] = pk0[2 * kk][0]; fu[1] = pk0[2 * kk][1];
        fu[2] = pk0[2 * kk + 1][0]; fu[3] = pk0[2 * kk + 1][1];
      } else {
        fu[0] = pk1[2 * kk][0]; fu[1] = pk1[2 * kk][1];
        fu[2] = pk1[2 * kk + 1][0]; fu[3] = pk1[2 * kk + 1][1];
      }
      const bf16x8 pa = *reinterpret_cast<const bf16x8*>(&fu[0]);
      const int oct = ((2 * ks + h) ^ so) * 8;
      const bf16x8 v0 = *reinterpret_cast<const bf16x8*>(&Vb[li32 * 64 + oct]);
      const bf16x8 v1 = *reinterpret_cast<const bf16x8*>(&Vb[(32 + li32) * 64 + oct]);
      oacc0 = mfma32(pa, v0, oacc0);
      oacc1 = mfma32(pa, v1, oacc1);
    }
    __builtin_amdgcn_s_setprio(0);
  }

  // ---- finalize: combine half-row sums once, divide, store bf16 ----
  const float lt = lrun + __shfl_xor(lrun, 32);
  ushort* ob = attnB + (size_t)bn * 65536;
#pragma unroll
  for (int r = 0; r < 16; ++r) {
    const int rp = (r & 3) + 8 * (r >> 2) + 4 * h;
    const float linv = 1.0f / __shfl(lt, rp);
    const size_t qrow = (size_t)(qb + w * 32 + rp) * 64;
    ob[qrow + li32] = f2bf(oacc0[r] * linv);
    ob[qrow + 32 + li32] = f2bf(oacc1[r] * linv);
  }
}

// ---------------------------------------------------------------------------
extern "C" void kernel_launch(void* const* d_in, const int* in_sizes, int n_in,
                              void* d_out, int out_size, void* d_ws, size_t ws_size,
                              hipStream_t stream) {
  const float* q_x = (const float*)d_in[0];
  const float* k_x = (const float*)d_in[1];
  const float* v_x = (const float*)d_in[2];
  const float* Wq  = (const float*)d_in[3];
  const float* bq  = (const float*)d_in[4];
  const float* Wk  = (const float*)d_in[5];
  const float* bk  = (const float*)d_in[6];
  const float* Wv  = (const float*)d_in[7];
  const float* bv  = (const float*)d_in[8];
  const float* Wo  = (const float*)d_in[9];
  const float* bo  = (const float*)d_in[10];
  const float* krw = (const float*)d_in[11];
  const float* krh = (const float*)d_in[12];

  ushort* wsQ  = (ushort*)d_ws;                 // [64][1024][64] bf16   8 MB
  ushort* wsK  = wsQ + 4194304;                 // 8 MB
  ushort* wsV  = wsK + 4194304;                 // [64][64][1024] bf16   8 MB
  ushort* xT   = wsV + 4194304;                 // 3 x [8][1024][256]   12 MB
  ushort* WsBf = xT + 6291456;                  // Wq|Wk|Wv|Wo bf16    852 KB
  ushort* attnB = WsBf + 425984;                // [8][512][1024] bf16   8 MB

  prep_all<<<1744, 256, 0, stream>>>(q_x, k_x, v_x, Wq, Wk, Wv, Wo, xT, WsBf);

  conv_qkv<<<dim3(16, 2, 24), 256, 0, stream>>>(xT, WsBf, bq, bk, bv, wsQ, wsK, wsV);

  attn_mfma<<<512, 256, 0, stream>>>(wsQ, wsK, wsV, krw, krh, attnB);

  outconv_mfma<<<dim3(32, 8), 128, 0, stream>>>(attnB, WsBf + 393216, bo, (float*)d_out);
}